// Round 2
// baseline (2896.628 us; speedup 1.0000x reference)
//
#include <hip/hip_runtime.h>

// EncoderLayer: S=50, L=1024, D=768, D4=192. fp32 inputs/output, bf16 MFMA
// compute internally (fp32 accumulate). 5 stages: self-attn, MLP, cross-step
// attn, self-attn, MLP. GEMM: MFMA 16x16x32 bf16, 64x64x64 tiles.
// Weights (fp32 global) are converted to bf16 during LDS staging (BF32 path).

typedef __bf16 bf16x8 __attribute__((ext_vector_type(8)));
typedef float f32x4 __attribute__((ext_vector_type(4)));

// ---------------- batched GEMM: C[M,N] = A[M,K] * B + bias, opt relu -------
// A: bf16 [M,K] row-major. BNN=1: B is [K,N] row-major; BNN=0: B is [N,K]
// (B^T given, bf16 only). BF32=1: B is fp32 (converted during staging).
// K = padded (mult of 64) loop bound; Kb = true K for NN B loads. A's padded
// K cols must be zero (only cross probs padded; softmax zeroes them).
template<int BNN, int BF32>
__global__ __launch_bounds__(256) void gemm_k(
    const __bf16* __restrict__ A, const void* __restrict__ Bv, __bf16* __restrict__ C,
    int M, int N, int K, int Kb,
    int lda, int ldb, int ldc,
    long long sA, long long sB, long long sC,
    const float* __restrict__ bias, long long sBias, int relu)
{
    __shared__ __bf16 As[64][72];   // +8 pad to break bank conflicts
    __shared__ __bf16 Bs[64][72];   // Bs[n][k]

    const int batch = blockIdx.z;
    A += (long long)batch * sA;
    C += (long long)batch * sC;

    const int m0 = blockIdx.x * 64;
    const int n0 = blockIdx.y * 64;
    const int tid = threadIdx.x;
    const int lane = tid & 63;
    const int wave = tid >> 6;
    const int wr = wave >> 1, wc = wave & 1;   // 2x2 waves, 32x32 each

    f32x4 acc[2][2];
    #pragma unroll
    for (int i = 0; i < 2; i++)
        #pragma unroll
        for (int j = 0; j < 2; j++)
            acc[i][j] = f32x4{0.f, 0.f, 0.f, 0.f};

    for (int kb = 0; kb < K; kb += 64) {
        // ---- stage A tile: 64 rows x 64 k, 4 threads/row x 16 elems (bf16)
        {
            const int row = tid >> 2;
            const int cs = (tid & 3) << 4;
            const int gr = m0 + row;
            __bf16* dst = &As[row][cs];
            if (gr < M) {
                const __bf16* src = A + (long long)gr * lda + kb + cs;
                *(bf16x8*)dst       = *(const bf16x8*)src;
                *(bf16x8*)(dst + 8) = *(const bf16x8*)(src + 8);
            } else {
                #pragma unroll
                for (int i = 0; i < 16; i++) dst[i] = (__bf16)0.f;
            }
        }
        // ---- stage B tile into Bs[n][k]
        if (BNN) {
            const int kk = tid >> 2;              // k within tile
            const int ns = (tid & 3) << 4;        // n segment
            const int gk = kb + kk;
            const bool kok = gk < Kb;
            if (BF32) {
                const float* src = (const float*)Bv + (long long)batch * sB
                                 + (long long)gk * ldb + n0 + ns;
                if (kok && (n0 + ns + 16 <= N)) {
                    #pragma unroll
                    for (int q = 0; q < 4; q++) {
                        float4 v = *(const float4*)(src + 4 * q);
                        Bs[ns + 4 * q + 0][kk] = (__bf16)v.x;
                        Bs[ns + 4 * q + 1][kk] = (__bf16)v.y;
                        Bs[ns + 4 * q + 2][kk] = (__bf16)v.z;
                        Bs[ns + 4 * q + 3][kk] = (__bf16)v.w;
                    }
                } else {
                    for (int i = 0; i < 16; i++) {
                        const int n = n0 + ns + i;
                        Bs[ns + i][kk] = (kok && n < N) ? (__bf16)src[i] : (__bf16)0.f;
                    }
                }
            } else {
                const __bf16* src = (const __bf16*)Bv + (long long)batch * sB
                                  + (long long)gk * ldb + n0 + ns;
                if (kok && (n0 + ns + 16 <= N)) {
                    bf16x8 v0 = *(const bf16x8*)src;
                    bf16x8 v1 = *(const bf16x8*)(src + 8);
                    #pragma unroll
                    for (int i = 0; i < 8; i++) Bs[ns + i][kk] = v0[i];
                    #pragma unroll
                    for (int i = 0; i < 8; i++) Bs[ns + 8 + i][kk] = v1[i];
                } else {
                    for (int i = 0; i < 16; i++) {
                        const int n = n0 + ns + i;
                        Bs[ns + i][kk] = (kok && n < N) ? src[i] : (__bf16)0.f;
                    }
                }
            }
        } else {
            // B^T given (bf16): rows are n
            const int row = tid >> 2;
            const int cs = (tid & 3) << 4;
            const int gn = n0 + row;
            __bf16* dst = &Bs[row][cs];
            if (gn < N) {
                const __bf16* src = (const __bf16*)Bv + (long long)batch * sB
                                  + (long long)gn * ldb + kb + cs;
                *(bf16x8*)dst       = *(const bf16x8*)src;
                *(bf16x8*)(dst + 8) = *(const bf16x8*)(src + 8);
            } else {
                #pragma unroll
                for (int i = 0; i < 16; i++) dst[i] = (__bf16)0.f;
            }
        }
        __syncthreads();

        // ---- MFMA: A-frag A[m=lane&15][k=(lane>>4)*8+j], B-frag mirrored
        #pragma unroll
        for (int ks = 0; ks < 64; ks += 32) {
            const int kf = ks + ((lane >> 4) << 3);
            bf16x8 av[2], bv[2];
            #pragma unroll
            for (int mi = 0; mi < 2; mi++)
                av[mi] = *(const bf16x8*)&As[wr * 32 + mi * 16 + (lane & 15)][kf];
            #pragma unroll
            for (int ni = 0; ni < 2; ni++)
                bv[ni] = *(const bf16x8*)&Bs[wc * 32 + ni * 16 + (lane & 15)][kf];
            #pragma unroll
            for (int mi = 0; mi < 2; mi++)
                #pragma unroll
                for (int ni = 0; ni < 2; ni++)
                    acc[mi][ni] = __builtin_amdgcn_mfma_f32_16x16x32_bf16(
                        av[mi], bv[ni], acc[mi][ni], 0, 0, 0);
        }
        __syncthreads();
    }

    // ---- epilogue: C/D layout col=lane&15, row=(lane>>4)*4+reg  [m89-verified]
    const int rb = (lane >> 4) << 2;
    const int cc = lane & 15;
    #pragma unroll
    for (int mi = 0; mi < 2; mi++) {
        #pragma unroll
        for (int ni = 0; ni < 2; ni++) {
            const int col = n0 + wc * 32 + ni * 16 + cc;
            if (col >= N) continue;
            float bvl = 0.f;
            if (bias) bvl = bias[(long long)batch * sBias + col];
            #pragma unroll
            for (int r = 0; r < 4; r++) {
                const int row = m0 + wr * 32 + mi * 16 + rb + r;
                if (row < M) {
                    float v = acc[mi][ni][r] + bvl;
                    if (relu) v = fmaxf(v, 0.f);
                    C[(long long)row * ldc + col] = (__bf16)v;
                }
            }
        }
    }
}

// ---------------- reductions ----------------
__device__ __forceinline__ float wave_sum(float v) {
    #pragma unroll
    for (int o = 32; o > 0; o >>= 1) v += __shfl_xor(v, o);
    return v;
}
__device__ __forceinline__ float wave_max(float v) {
    #pragma unroll
    for (int o = 32; o > 0; o >>= 1) v = fmaxf(v, __shfl_xor(v, o));
    return v;
}

// softmax over 1024 cols, in-place bf16, scale applied inside exp
__global__ __launch_bounds__(256) void softmax_self_k(__bf16* __restrict__ u, float scale) {
    __shared__ float red[4];
    const long long row = blockIdx.x;
    __bf16* p = u + row * 1024;
    const int t = threadIdx.x;
    float v[4];
    float mx = -1e30f;
    #pragma unroll
    for (int i = 0; i < 4; i++) { v[i] = (float)p[t + i * 256]; mx = fmaxf(mx, v[i]); }
    mx = wave_max(mx);
    if ((t & 63) == 0) red[t >> 6] = mx;
    __syncthreads();
    mx = fmaxf(fmaxf(red[0], red[1]), fmaxf(red[2], red[3]));
    float s = 0.f;
    #pragma unroll
    for (int i = 0; i < 4; i++) { v[i] = __expf(scale * (v[i] - mx)); s += v[i]; }
    s = wave_sum(s);
    __syncthreads();
    if ((t & 63) == 0) red[t >> 6] = s;
    __syncthreads();
    s = red[0] + red[1] + red[2] + red[3];
    const float inv = 1.f / s;
    #pragma unroll
    for (int i = 0; i < 4; i++) p[t + i * 256] = (__bf16)(v[i] * inv);
}

// cross softmax: rows of 50 valid cols in a 64-wide padded row; pads -> 0
__global__ __launch_bounds__(64) void softmax_cross_k(__bf16* __restrict__ u, float scale) {
    const long long row = blockIdx.x;
    __bf16* p = u + row * 64;
    const int lane = threadIdx.x;
    float v = (lane < 50) ? (float)p[lane] : -1e30f;
    float mx = wave_max(v);
    float e = (lane < 50) ? __expf(scale * (v - mx)) : 0.f;
    float s = wave_sum(e);
    p[lane] = (__bf16)(e / s);
}

// out = LN(x + h) * g + b. g/b are fp32. mode 0: rows [S*L], g/b per s=(r>>10).
// mode 1 (cross): rows are [L*S] (r=l*50+s), shared g/b, out row = s*1024+l.
// outf32: write fp32 (d_out) instead of bf16 (workspace).
__global__ __launch_bounds__(256) void add_ln_k(
    const __bf16* __restrict__ x, const __bf16* __restrict__ h, void* __restrict__ out,
    const float* __restrict__ g, const float* __restrict__ b, int mode, int outf32)
{
    __shared__ float red[4];
    const long long r = blockIdx.x;
    const __bf16* xr = x + r * 768;
    const __bf16* hr = h + r * 768;
    long long orow; const float *gp, *bp;
    if (mode == 0) {
        orow = r;
        const long long s = r >> 10;
        gp = g + s * 768; bp = b + s * 768;
    } else {
        const long long l = r / 50, s2 = r % 50;
        orow = s2 * 1024 + l;
        gp = g; bp = b;
    }
    const int t = threadIdx.x;
    float v[3]; float sum = 0.f;
    #pragma unroll
    for (int i = 0; i < 3; i++) { const int d = t + i * 256; v[i] = (float)xr[d] + (float)hr[d]; sum += v[i]; }
    sum = wave_sum(sum);
    if ((t & 63) == 0) red[t >> 6] = sum;
    __syncthreads();
    const float mean = (red[0] + red[1] + red[2] + red[3]) * (1.f / 768.f);
    float vs = 0.f;
    #pragma unroll
    for (int i = 0; i < 3; i++) { const float d = v[i] - mean; vs += d * d; }
    vs = wave_sum(vs);
    __syncthreads();
    if ((t & 63) == 0) red[t >> 6] = vs;
    __syncthreads();
    const float rstd = rsqrtf((red[0] + red[1] + red[2] + red[3]) * (1.f / 768.f) + 1e-5f);
    #pragma unroll
    for (int i = 0; i < 3; i++) {
        const int d = t + i * 256;
        const float o = (v[i] - mean) * rstd * gp[d] + bp[d];
        if (outf32) ((float*)out)[orow * 768 + d] = o;
        else        ((__bf16*)out)[orow * 768 + d] = (__bf16)o;
    }
}

// [S,L,D] -> [L,S,D] (bf16 ws -> bf16 ws)
__global__ __launch_bounds__(256) void transpose_sl_k(const __bf16* __restrict__ in,
                                                      __bf16* __restrict__ out) {
    const long long r = blockIdx.x;              // s*1024 + l
    const long long s = r >> 10, l = r & 1023;
    const __bf16* ir = in + r * 768;
    __bf16* orow = out + (l * 50 + s) * 768;
    for (int i = threadIdx.x; i < 768; i += 256) orow[i] = ir[i];
}

// fp32 -> bf16, 8 elems/thread
__global__ __launch_bounds__(256) void cvt_f32_bf16_k(const float* __restrict__ in,
                                                      __bf16* __restrict__ out) {
    const long long i = ((long long)blockIdx.x * 256 + threadIdx.x) * 8;
    float4 a = *(const float4*)(in + i);
    float4 b = *(const float4*)(in + i + 4);
    bf16x8 o;
    o[0] = (__bf16)a.x; o[1] = (__bf16)a.y; o[2] = (__bf16)a.z; o[3] = (__bf16)a.w;
    o[4] = (__bf16)b.x; o[5] = (__bf16)b.y; o[6] = (__bf16)b.z; o[7] = (__bf16)b.w;
    *(bf16x8*)(out + i) = o;
}

extern "C" void kernel_launch(void* const* d_in, const int* in_sizes, int n_in,
                              void* d_out, int out_size, void* d_ws, size_t ws_size,
                              hipStream_t stream)
{
    const float SCALE = 0.07216878364870322f;   // 1/sqrt(192)
    auto inf = [&](int i) { return (const float*)d_in[i]; };

    // workspace carve (bytes): all 16B-aligned offsets
    char* w = (char*)d_ws;
    __bf16* xw = (__bf16*)(w + 0LL);            // [S,L,D]   current x (bf16)
    __bf16* hw = (__bf16*)(w + 78643200LL);     // [S,L,D]   h
    __bf16* tw = (__bf16*)(w + 157286400LL);    // [S,L,D]   t = a@x
    __bf16* xt = (__bf16*)(w + 235929600LL);    // [L,S,D]   cross transpose
    __bf16* qw = (__bf16*)(w + 314572800LL);    // [S,L,D4]
    __bf16* kw = (__bf16*)(w + 334233600LL);    // [S,L,D4]
    __bf16* G  = (__bf16*)(w + 353894400LL);    // [S,L,L] scores/probs (bf16)
    if (ws_size < 458752000ULL) return;         // insufficient scratch

    // weight GEMM: A bf16 ws, B fp32 global [K,N]
    auto gemm_w = [&](const __bf16* A, const float* B, __bf16* C,
                      int M, int N, int K, int lda, int ldb, int ldc,
                      long long sA, long long sB, long long sC, int batch,
                      const float* bias, long long sBias, int relu) {
        dim3 grid((M + 63) / 64, (N + 63) / 64, batch);
        gemm_k<1, 1><<<grid, dim3(256), 0, stream>>>(A, B, C, M, N, K, K, lda, ldb, ldc,
                                                     sA, sB, sC, bias, sBias, relu);
    };
    // activation GEMM: A,B bf16 ws, B [K,N]
    auto gemm_a = [&](const __bf16* A, const __bf16* B, __bf16* C,
                      int M, int N, int K, int Kb, int lda, int ldb, int ldc,
                      long long sA, long long sB, long long sC, int batch) {
        dim3 grid((M + 63) / 64, (N + 63) / 64, batch);
        gemm_k<1, 0><<<grid, dim3(256), 0, stream>>>(A, B, C, M, N, K, Kb, lda, ldb, ldc,
                                                     sA, sB, sC, nullptr, 0, 0);
    };
    // NT GEMM: A,B bf16 ws, B given as [N,K]
    auto gemm_nt = [&](const __bf16* A, const __bf16* B, __bf16* C,
                       int M, int N, int K, int lda, int ldb, int ldc,
                       long long sA, long long sB, long long sC, int batch) {
        dim3 grid((M + 63) / 64, (N + 63) / 64, batch);
        gemm_k<0, 0><<<grid, dim3(256), 0, stream>>>(A, B, C, M, N, K, K, lda, ldb, ldc,
                                                     sA, sB, sC, nullptr, 0, 0);
    };

    // x (fp32) -> xw (bf16)
    cvt_f32_bf16_k<<<19200, 256, 0, stream>>>(inf(0), xw);

    auto self_attn = [&](const float* Wq, const float* Wk, const float* Wv,
                         const float* g, const float* b) {
        gemm_w(xw, Wq, qw, 1024, 192, 768, 768, 192, 192,
               786432LL, 147456LL, 196608LL, 50, nullptr, 0, 0);
        gemm_w(xw, Wk, kw, 1024, 192, 768, 768, 192, 192,
               786432LL, 147456LL, 196608LL, 50, nullptr, 0, 0);
        gemm_nt(qw, kw, G, 1024, 1024, 192, 192, 192, 1024,
                196608LL, 196608LL, 1048576LL, 50);
        softmax_self_k<<<51200, 256, 0, stream>>>(G, SCALE);
        gemm_a(G, xw, tw, 1024, 768, 1024, 1024, 1024, 768, 768,
               1048576LL, 786432LL, 786432LL, 50);
        gemm_w(tw, Wv, hw, 1024, 768, 768, 768, 768, 768,
               786432LL, 589824LL, 786432LL, 50, nullptr, 0, 0);
        add_ln_k<<<51200, 256, 0, stream>>>(xw, hw, xw, g, b, 0, 0);
    };
    auto mlp = [&](const float* W1, const float* b1, const float* W2, const float* b2,
                   const float* g, const float* b, void* outp, int outf32) {
        gemm_w(xw, W1, qw, 1024, 192, 768, 768, 192, 192,
               786432LL, 147456LL, 196608LL, 50, b1, 192LL, 1);
        gemm_w(qw, W2, hw, 1024, 768, 192, 192, 768, 768,
               196608LL, 147456LL, 786432LL, 50, b2, 768LL, 0);
        add_ln_k<<<51200, 256, 0, stream>>>(xw, hw, outp, g, b, 0, outf32);
    };

    // stage 1: pre self-attn + ln1
    self_attn(inf(1), inf(2), inf(3), inf(4), inf(5));
    // stage 2: pre MLP + ln4p
    mlp(inf(6), inf(7), inf(8), inf(9), inf(10), inf(11), xw, 0);

    // stage 3: cross-step attention + ln2 (shared weights)
    transpose_sl_k<<<51200, 256, 0, stream>>>(xw, xt);
    gemm_w(xt, inf(12), qw, 51200, 192, 768, 768, 192, 192, 0, 0, 0, 1, nullptr, 0, 0);
    gemm_w(xt, inf(13), kw, 51200, 192, 768, 768, 192, 192, 0, 0, 0, 1, nullptr, 0, 0);
    gemm_nt(qw, kw, G, 50, 50, 192, 192, 192, 64, 9600LL, 9600LL, 3200LL, 1024);
    softmax_cross_k<<<51200, 64, 0, stream>>>(G, SCALE);
    gemm_a(G, xt, tw, 50, 768, 64, 50, 64, 768, 768,
           3200LL, 38400LL, 38400LL, 1024);
    gemm_w(tw, inf(14), hw, 51200, 768, 768, 768, 768, 768, 0, 0, 0, 1, nullptr, 0, 0);
    add_ln_k<<<51200, 256, 0, stream>>>(xt, hw, xw, inf(15), inf(16), 1, 0);

    // stage 4: post self-attn + ln3
    self_attn(inf(17), inf(18), inf(19), inf(20), inf(21));
    // stage 5: post MLP + ln4 -> d_out (fp32)
    mlp(inf(22), inf(23), inf(24), inf(25), inf(26), inf(27), d_out, 1);
}